// Round 5
// baseline (607.029 us; speedup 1.0000x reference)
//
#include <hip/hip_runtime.h>
#include <hip/hip_bf16.h>

#define N_NODES 50000
#define N_EDGES 800000
#define F 128
#define BN_EPS 1e-5f
#define SLOPE 0.01f
#define LROW 136  // LDS row stride in shorts (128 + 8 pad)

typedef __attribute__((ext_vector_type(8))) __bf16 bf16x8_t;
typedef __attribute__((ext_vector_type(8))) unsigned short u16x8_t;
typedef __attribute__((ext_vector_type(4))) float f32x4_t;

__device__ __forceinline__ unsigned short f2b(float f) {
    unsigned int u = __float_as_uint(f);
    unsigned int r = (u + 0x7fffu + ((u >> 16) & 1u)) >> 16;  // RNE
    return (unsigned short)r;
}
__device__ __forceinline__ float b2f_lo(unsigned int v) { return __uint_as_float(v << 16); }
__device__ __forceinline__ float b2f_hi(unsigned int v) { return __uint_as_float(v & 0xffff0000u); }

// ---------------- CSR build (once per call, reused across 4 layers) ----------------

__global__ void hist_kernel(const int* __restrict__ dst, int* __restrict__ deg) {
    int e = blockIdx.x * blockDim.x + threadIdx.x;
    if (e < N_EDGES) atomicAdd(&deg[dst[e]], 1);
}

// parallel CSR range allocation: ranges need not be monotonic in node index.
__global__ __launch_bounds__(256) void alloc_kernel(const int* __restrict__ deg,
                                                    int* __restrict__ row_start,
                                                    int* __restrict__ cursor,
                                                    float* __restrict__ inv_deg,
                                                    int* __restrict__ counter) {
    int i = blockIdx.x * blockDim.x + threadIdx.x;
    int lane = threadIdx.x & 63;
    int d = (i < N_NODES) ? deg[i] : 0;
    int incl = d;
#pragma unroll
    for (int off = 1; off < 64; off <<= 1) {
        int v = __shfl_up(incl, off);
        if (lane >= off) incl += v;
    }
    int total = __shfl(incl, 63);
    int base = 0;
    if (lane == 63) base = atomicAdd(counter, total);
    base = __shfl(base, 63);
    if (i < N_NODES) {
        int start = base + incl - d;
        row_start[i] = start;
        cursor[i] = start;
        inv_deg[i] = (d > 0) ? (1.0f / (float)d) : 0.0f;
    }
}

__global__ void fill_kernel(const int* __restrict__ src, const int* __restrict__ dst,
                            int* __restrict__ cursor, int* __restrict__ csr_src) {
    int e = blockIdx.x * blockDim.x + threadIdx.x;
    if (e < N_EDGES) {
        int pos = atomicAdd(&cursor[dst[e]], 1);
        csr_src[pos] = src[e];
    }
}

// ---------------- prep: fp32 -> bf16 conversions ----------------

__global__ __launch_bounds__(256) void f2b_kernel(const float* __restrict__ in,
                                                  unsigned short* __restrict__ out) {
    long i = (long)blockIdx.x * blockDim.x + threadIdx.x;  // float4 index
    if (i >= (long)N_NODES * (F / 4)) return;
    float4 v = ((const float4*)in)[i];
    ushort4 o;
    o.x = f2b(v.x); o.y = f2b(v.y); o.z = f2b(v.z); o.w = f2b(v.w);
    ((ushort4*)out)[i] = o;
}

// Wt[i][n][k] (k: 0..127 from Wl[i][k][n], 128..255 from Wr[i][k-128][n])
__global__ __launch_bounds__(256) void wprep_kernel(const float* __restrict__ Wl,
                                                    const float* __restrict__ Wr,
                                                    unsigned short* __restrict__ Wt) {
    int idx = blockIdx.x * blockDim.x + threadIdx.x;  // 4*128*256 = 131072
    if (idx >= 4 * F * 256) return;
    int k = idx & 255;
    int n = (idx >> 8) & 127;
    int i = idx >> 15;
    float v = (k < F) ? Wl[((long)i * F + k) * F + n] : Wr[((long)i * F + (k - F)) * F + n];
    Wt[idx] = f2b(v);
}

// ---------------- fused layer: gather-mean -> MFMA -> leaky -> store + BN sums ------
// block = 256 threads = 4 waves, 64 nodes/block; wave handles 16 nodes privately:
// phase 1 gathers neighbor means into its own LDS rows (no barrier needed),
// phase 2 uses them as MFMA A-operand (agg half from LDS, hin half from global).

__global__ __launch_bounds__(256) void fused_layer(const unsigned short* __restrict__ hin,
                                                   const int* __restrict__ row_start,
                                                   const int* __restrict__ deg,
                                                   const int* __restrict__ csr_src,
                                                   const float* __restrict__ inv_deg,
                                                   const unsigned short* __restrict__ Wt,
                                                   const float* __restrict__ bl,
                                                   float* __restrict__ Pf,
                                                   unsigned short* __restrict__ Pb,
                                                   int write_bf16,
                                                   float* __restrict__ sum,
                                                   float* __restrict__ sumsq) {
    __shared__ unsigned short agg_lds[4 * 16 * LROW];
    __shared__ float lsum[4][F];
    __shared__ float lsq[4][F];

    const int tid = threadIdx.x;
    const int wave = tid >> 6, lane = tid & 63;
    const int rbase = blockIdx.x * 64 + wave * 16;
    unsigned short* myrows = agg_lds + wave * 16 * LROW;

    // ---- phase 1: gather-mean for 16 nodes (lane = 2 feature columns) ----
    const unsigned short* hl = hin + lane * 2;
    for (int n = 0; n < 16; ++n) {
        const int node = rbase + n;
        float ax = 0.f, ay = 0.f;
        if (node < N_NODES) {
            const int beg = row_start[node];
            const int end = beg + deg[node];
            for (int e = beg; e < end; e += 8) {
                int idx[8];
#pragma unroll
                for (int j = 0; j < 8; ++j) {
                    int ee = e + j;
                    idx[j] = csr_src[(ee < end) ? ee : beg];
                }
                unsigned int v[8];
#pragma unroll
                for (int j = 0; j < 8; ++j)
                    v[j] = *(const unsigned int*)(hl + (long)idx[j] * F);
#pragma unroll
                for (int j = 0; j < 8; ++j) {
                    unsigned int mask = (e + j < end) ? v[j] : 0u;
                    ax += b2f_lo(mask);
                    ay += b2f_hi(mask);
                }
            }
            const float inv = inv_deg[node];
            ax *= inv; ay *= inv;
        }
        unsigned int o = (unsigned int)f2b(ax) | ((unsigned int)f2b(ay) << 16);
        *(unsigned int*)(myrows + n * LROW + lane * 2) = o;
    }
    // wave-private LDS: no barrier needed between phases

    // ---- phase 2: MFMA over K=256 ([agg(LDS) | hin(global)] @ Wt^T) ----
    const int m = lane & 15, q = lane >> 4;
    const int arow = rbase + m;
    const bool aval = arow < N_NODES;
    const unsigned short* ar = myrows + m * LROW + q * 8;         // agg A-frag base
    const unsigned short* hp = hin + (long)arow * F + q * 8;      // hin A-frag base
    const unsigned short* wb = Wt + q * 8 + m * 256;

    f32x4_t acc[8];
#pragma unroll
    for (int nt = 0; nt < 8; ++nt) acc[nt] = (f32x4_t){0.f, 0.f, 0.f, 0.f};

#pragma unroll
    for (int ks = 0; ks < 8; ++ks) {
        u16x8_t av;
        if (ks < 4) {
            av = *(const u16x8_t*)(ar + ks * 32);
        } else {
            av = (u16x8_t)0;
            if (aval) av = *(const u16x8_t*)(hp + (ks - 4) * 32);
        }
        bf16x8_t af = __builtin_bit_cast(bf16x8_t, av);
#pragma unroll
        for (int nt = 0; nt < 8; ++nt) {
            u16x8_t bv = *(const u16x8_t*)(wb + (long)nt * 16 * 256 + ks * 32);
            bf16x8_t bf = __builtin_bit_cast(bf16x8_t, bv);
            acc[nt] = __builtin_amdgcn_mfma_f32_16x16x32_bf16(af, bf, acc[nt], 0, 0, 0);
        }
    }

    // ---- epilogue: bias + leaky + store + BN column partials ----
    float cs[8], cq[8];
    const int rw = rbase + q * 4;
#pragma unroll
    for (int nt = 0; nt < 8; ++nt) {
        cs[nt] = 0.f; cq[nt] = 0.f;
        const int c = nt * 16 + m;
        const float b = bl[c];
#pragma unroll
        for (int r = 0; r < 4; ++r) {
            const int grow = rw + r;
            if (grow < N_NODES) {
                float v = acc[nt][r] + b;
                v = (v >= 0.f) ? v : SLOPE * v;
                if (write_bf16) {
                    Pb[(long)grow * F + c] = f2b(v);
                } else {
                    Pf[(long)grow * F + c] = v;
                }
                cs[nt] += v;
                cq[nt] += v * v;
            }
        }
    }
#pragma unroll
    for (int nt = 0; nt < 8; ++nt) {
        cs[nt] += __shfl_xor(cs[nt], 16);
        cs[nt] += __shfl_xor(cs[nt], 32);
        cq[nt] += __shfl_xor(cq[nt], 16);
        cq[nt] += __shfl_xor(cq[nt], 32);
    }
    if (lane < 16) {
#pragma unroll
        for (int nt = 0; nt < 8; ++nt) {
            lsum[wave][nt * 16 + m] = cs[nt];
            lsq[wave][nt * 16 + m] = cq[nt];
        }
    }
    __syncthreads();
    if (tid < F) {
        float s = 0.f, s2 = 0.f;
#pragma unroll
        for (int w = 0; w < 4; ++w) {
            s += lsum[w][tid];
            s2 += lsq[w][tid];
        }
        atomicAdd(&sum[tid], s);
        atomicAdd(&sumsq[tid], s2);
    }
}

__global__ void bn_prep(const float* __restrict__ sum, const float* __restrict__ sumsq,
                        const float* __restrict__ gamma, const float* __restrict__ beta,
                        float* __restrict__ scale, float* __restrict__ shift) {
    int j = threadIdx.x;
    if (j < F) {
        const float inv_n = 1.0f / (float)N_NODES;
        float mu = sum[j] * inv_n;
        float var = sumsq[j] * inv_n - mu * mu;
        float scl = gamma[j] * rsqrtf(var + BN_EPS);
        scale[j] = scl;
        shift[j] = beta[j] - mu * scl;
    }
}

// bf16 P -> bf16 h_next (layers 0-2): 8 features per thread
__global__ __launch_bounds__(256) void bn_apply_b(const unsigned short* __restrict__ Pb,
                                                  unsigned short* __restrict__ outb,
                                                  const float* __restrict__ scale,
                                                  const float* __restrict__ shift) {
    long i = (long)blockIdx.x * blockDim.x + threadIdx.x;  // uint4 index (8 bf16)
    if (i >= (long)N_NODES * (F / 8)) return;
    const int c8 = (int)(i & 15);  // feature block
    uint4 v = ((const uint4*)Pb)[i];
    const float4 sc0 = ((const float4*)scale)[c8 * 2];
    const float4 sc1 = ((const float4*)scale)[c8 * 2 + 1];
    const float4 sh0 = ((const float4*)shift)[c8 * 2];
    const float4 sh1 = ((const float4*)shift)[c8 * 2 + 1];
    uint4 o;
    o.x = (unsigned int)f2b(b2f_lo(v.x) * sc0.x + sh0.x) |
          ((unsigned int)f2b(b2f_hi(v.x) * sc0.y + sh0.y) << 16);
    o.y = (unsigned int)f2b(b2f_lo(v.y) * sc0.z + sh0.z) |
          ((unsigned int)f2b(b2f_hi(v.y) * sc0.w + sh0.w) << 16);
    o.z = (unsigned int)f2b(b2f_lo(v.z) * sc1.x + sh1.x) |
          ((unsigned int)f2b(b2f_hi(v.z) * sc1.y + sh1.y) << 16);
    o.w = (unsigned int)f2b(b2f_lo(v.w) * sc1.z + sh1.z) |
          ((unsigned int)f2b(b2f_hi(v.w) * sc1.w + sh1.w) << 16);
    ((uint4*)outb)[i] = o;
}

// fp32 P -> fp32 out, in place (final layer)
__global__ __launch_bounds__(256) void bn_apply_f(float* __restrict__ P,
                                                  const float* __restrict__ scale,
                                                  const float* __restrict__ shift) {
    long i = (long)blockIdx.x * blockDim.x + threadIdx.x;  // float4 index
    if (i >= (long)N_NODES * (F / 4)) return;
    const int c4 = (int)(i & 31);
    float4 v = ((float4*)P)[i];
    const float4 sc = ((const float4*)scale)[c4];
    const float4 sh = ((const float4*)shift)[c4];
    v.x = v.x * sc.x + sh.x;
    v.y = v.y * sc.y + sh.y;
    v.z = v.z * sc.z + sh.z;
    v.w = v.w * sc.w + sh.w;
    ((float4*)P)[i] = v;
}

// ---------------- launch ----------------

extern "C" void kernel_launch(void* const* d_in, const int* in_sizes, int n_in,
                              void* d_out, int out_size, void* d_ws, size_t ws_size,
                              hipStream_t stream) {
    const float* x     = (const float*)d_in[0];
    const int*   ei    = (const int*)d_in[1];
    const float* Wl    = (const float*)d_in[2];
    const float* bl    = (const float*)d_in[3];
    const float* Wr    = (const float*)d_in[4];
    const float* gamma = (const float*)d_in[5];
    const float* beta  = (const float*)d_in[6];
    float* out = (float*)d_out;

    const int* src = ei;
    const int* dst = ei + N_EDGES;

    char* w = (char*)d_ws;
    auto alloc = [&](size_t bytes) -> char* {
        char* p = w;
        w += (bytes + 255) & ~(size_t)255;
        return p;
    };
    unsigned short* hbA   = (unsigned short*)alloc((size_t)N_NODES * F * 2);
    unsigned short* hbB   = (unsigned short*)alloc((size_t)N_NODES * F * 2);
    unsigned short* Wt    = (unsigned short*)alloc((size_t)4 * F * 256 * 2);
    int*   deg      = (int*)alloc((size_t)N_NODES * 4);
    int*   row_start= (int*)alloc((size_t)N_NODES * 4);
    int*   cursor   = (int*)alloc((size_t)N_NODES * 4);
    int*   csr_src  = (int*)alloc((size_t)N_EDGES * 4);
    float* inv_deg  = (float*)alloc((size_t)N_NODES * 4);
    float* sum      = (float*)alloc(F * 4);
    float* sumsq    = (float*)alloc(F * 4);
    float* scale    = (float*)alloc(F * 4);
    float* shift    = (float*)alloc(F * 4);
    int*   counter  = (int*)alloc(256);

    hipMemsetAsync(deg, 0, (size_t)N_NODES * 4, stream);
    hipMemsetAsync(counter, 0, 4, stream);

    hist_kernel<<<(N_EDGES + 255) / 256, 256, 0, stream>>>(dst, deg);
    alloc_kernel<<<(N_NODES + 255) / 256, 256, 0, stream>>>(deg, row_start, cursor, inv_deg,
                                                            counter);
    fill_kernel<<<(N_EDGES + 255) / 256, 256, 0, stream>>>(src, dst, cursor, csr_src);

    const int n4 = N_NODES * (F / 4);
    const int n8 = N_NODES * (F / 8);
    f2b_kernel<<<(n4 + 255) / 256, 256, 0, stream>>>(x, hbA);
    wprep_kernel<<<(4 * F * 256 + 255) / 256, 256, 0, stream>>>(Wl, Wr, Wt);

    unsigned short* Pb = (unsigned short*)out;  // reuse d_out as bf16 scratch (layers 0-2)

    unsigned short* hin = hbA;
    unsigned short* hnext = hbB;
    for (int i = 0; i < 4; ++i) {
        hipMemsetAsync(sum, 0, F * 4, stream);
        hipMemsetAsync(sumsq, 0, F * 4, stream);

        const int last = (i == 3);
        fused_layer<<<(N_NODES + 63) / 64, 256, 0, stream>>>(
            hin, row_start, deg, csr_src, inv_deg,
            Wt + (size_t)i * F * 256, bl + (size_t)i * F,
            out, Pb, last ? 0 : 1, sum, sumsq);

        bn_prep<<<1, 128, 0, stream>>>(sum, sumsq, gamma + (size_t)i * F, beta + (size_t)i * F,
                                       scale, shift);
        if (last) {
            bn_apply_f<<<(n4 + 255) / 256, 256, 0, stream>>>(out, scale, shift);
        } else {
            bn_apply_b<<<(n8 + 255) / 256, 256, 0, stream>>>(Pb, hnext, scale, shift);
        }

        unsigned short* t = hin; hin = hnext; hnext = t;
    }
}

// Round 6
// 504.653 us; speedup vs baseline: 1.2029x; 1.2029x over previous
//
#include <hip/hip_runtime.h>
#include <hip/hip_bf16.h>

#define N_NODES 50000
#define N_EDGES 800000
#define F 128
#define BN_EPS 1e-5f
#define SLOPE 0.01f

typedef __attribute__((ext_vector_type(8))) __bf16 bf16x8_t;
typedef __attribute__((ext_vector_type(8))) unsigned short u16x8_t;
typedef __attribute__((ext_vector_type(4))) float f32x4_t;

__device__ __forceinline__ unsigned short f2b(float f) {
    unsigned int u = __float_as_uint(f);
    unsigned int r = (u + 0x7fffu + ((u >> 16) & 1u)) >> 16;  // RNE
    return (unsigned short)r;
}
__device__ __forceinline__ float b2f_lo(unsigned int v) { return __uint_as_float(v << 16); }
__device__ __forceinline__ float b2f_hi(unsigned int v) { return __uint_as_float(v & 0xffff0000u); }

// ---------------- CSR build (once per call, reused across 4 layers) ----------------

__global__ void hist_kernel(const int* __restrict__ dst, int* __restrict__ deg) {
    int e = blockIdx.x * blockDim.x + threadIdx.x;
    if (e < N_EDGES) atomicAdd(&deg[dst[e]], 1);
}

// parallel CSR range allocation: ranges need not be monotonic in node index.
__global__ __launch_bounds__(256) void alloc_kernel(const int* __restrict__ deg,
                                                    int* __restrict__ row_start,
                                                    int* __restrict__ cursor,
                                                    float* __restrict__ inv_deg,
                                                    int* __restrict__ counter) {
    int i = blockIdx.x * blockDim.x + threadIdx.x;
    int lane = threadIdx.x & 63;
    int d = (i < N_NODES) ? deg[i] : 0;
    int incl = d;
#pragma unroll
    for (int off = 1; off < 64; off <<= 1) {
        int v = __shfl_up(incl, off);
        if (lane >= off) incl += v;
    }
    int total = __shfl(incl, 63);
    int base = 0;
    if (lane == 63) base = atomicAdd(counter, total);
    base = __shfl(base, 63);
    if (i < N_NODES) {
        int start = base + incl - d;
        row_start[i] = start;
        cursor[i] = start;
        inv_deg[i] = (d > 0) ? (1.0f / (float)d) : 0.0f;
    }
}

__global__ void fill_kernel(const int* __restrict__ src, const int* __restrict__ dst,
                            int* __restrict__ cursor, int* __restrict__ csr_src) {
    int e = blockIdx.x * blockDim.x + threadIdx.x;
    if (e < N_EDGES) {
        int pos = atomicAdd(&cursor[dst[e]], 1);
        csr_src[pos] = src[e];
    }
}

// ---------------- prep: fp32 -> bf16 conversions ----------------

__global__ __launch_bounds__(256) void f2b_kernel(const float* __restrict__ in,
                                                  unsigned short* __restrict__ out) {
    long i = (long)blockIdx.x * blockDim.x + threadIdx.x;  // float4 index
    if (i >= (long)N_NODES * (F / 4)) return;
    float4 v = ((const float4*)in)[i];
    ushort4 o;
    o.x = f2b(v.x); o.y = f2b(v.y); o.z = f2b(v.z); o.w = f2b(v.w);
    ((ushort4*)out)[i] = o;
}

// Wt[i][n][k] (k: 0..127 from Wl[i][k][n], 128..255 from Wr[i][k-128][n])
__global__ __launch_bounds__(256) void wprep_kernel(const float* __restrict__ Wl,
                                                    const float* __restrict__ Wr,
                                                    unsigned short* __restrict__ Wt) {
    int idx = blockIdx.x * blockDim.x + threadIdx.x;  // 4*128*256 = 131072
    if (idx >= 4 * F * 256) return;
    int k = idx & 255;
    int n = (idx >> 8) & 127;
    int i = idx >> 15;
    float v = (k < F) ? Wl[((long)i * F + k) * F + n] : Wr[((long)i * F + (k - F)) * F + n];
    Wt[idx] = f2b(v);
}

// ---------------- per-layer kernels ----------------

// one wave per node; lane holds 2 features; 8-way unrolled gather for MLP.
__global__ __launch_bounds__(256) void agg_kernel(const unsigned short* __restrict__ h,
                                                  const int* __restrict__ row_start,
                                                  const int* __restrict__ deg,
                                                  const int* __restrict__ csr_src,
                                                  const float* __restrict__ inv_deg,
                                                  unsigned short* __restrict__ agg) {
    int node = (int)((blockIdx.x * (unsigned)blockDim.x + threadIdx.x) >> 6);
    int lane = threadIdx.x & 63;
    if (node >= N_NODES) return;
    const int beg = row_start[node];
    const int end = beg + deg[node];
    const unsigned short* hl = h + lane * 2;
    float ax = 0.f, ay = 0.f;
    for (int e = beg; e < end; e += 8) {
        int idx[8];
#pragma unroll
        for (int j = 0; j < 8; ++j) {
            int ee = e + j;
            idx[j] = csr_src[(ee < end) ? ee : beg];
        }
        unsigned int v[8];
#pragma unroll
        for (int j = 0; j < 8; ++j)
            v[j] = *(const unsigned int*)(hl + (long)idx[j] * F);
#pragma unroll
        for (int j = 0; j < 8; ++j) {
            unsigned int m = (e + j < end) ? v[j] : 0u;
            ax += b2f_lo(m);
            ay += b2f_hi(m);
        }
    }
    float inv = inv_deg[node];
    unsigned int o = (unsigned int)f2b(ax * inv) | ((unsigned int)f2b(ay * inv) << 16);
    *(unsigned int*)(agg + (long)node * F + lane * 2) = o;
}

// MFMA GEMM with LDS-staged B (split-K halves, fragment-linear layout, conflict-free).
// block = 256 threads = 4 waves; wave: 16 rows x 128 cols; K=256.
__global__ __launch_bounds__(256) void gemm_mfma(const unsigned short* __restrict__ aggb,
                                                 const unsigned short* __restrict__ hin,
                                                 const unsigned short* __restrict__ Wt,
                                                 const float* __restrict__ bl,
                                                 float* __restrict__ Pf,
                                                 unsigned short* __restrict__ Pb,
                                                 int write_bf16,
                                                 float* __restrict__ sum,
                                                 float* __restrict__ sumsq) {
    __shared__ unsigned short bs[2048 * 8];  // 32 KB: one K-half of Wt, fragment-linear
    __shared__ float lsum[4][F];
    __shared__ float lsq[4][F];
    const int tid = threadIdx.x;
    const int wave = tid >> 6, lane = tid & 63;
    const int m = lane & 15, q = lane >> 4;
    const int rbase = blockIdx.x * 64 + wave * 16;
    const int arow = rbase + m;
    const bool aval = arow < N_NODES;
    const unsigned short* ap = aggb + (long)arow * F + q * 8;
    const unsigned short* hp = hin + (long)arow * F + q * 8;

    // prefetch all 8 A-fragments (independent 16B loads; latency overlaps staging)
    u16x8_t areg[8];
#pragma unroll
    for (int j = 0; j < 8; ++j) areg[j] = (u16x8_t)0;
    if (aval) {
#pragma unroll
        for (int j = 0; j < 4; ++j) areg[j] = *(const u16x8_t*)(ap + j * 32);
#pragma unroll
        for (int j = 0; j < 4; ++j) areg[4 + j] = *(const u16x8_t*)(hp + j * 32);
    }

    f32x4_t acc[8];
#pragma unroll
    for (int nt = 0; nt < 8; ++nt) acc[nt] = (f32x4_t){0.f, 0.f, 0.f, 0.f};

    for (int half = 0; half < 2; ++half) {
        if (half) __syncthreads();  // protect bs from previous half's readers
        // stage 32 KB: frag fid=(nt*4+ks)*64+lane holds Wt[nt*16+(lane&15)][half*128+ks*32+(lane>>4)*8 ..+8]
#pragma unroll
        for (int f = 0; f < 8; ++f) {
            const int fid = f * 256 + tid;  // 0..2047
            const int lf = fid & 63;
            const int ksf = (fid >> 6) & 3;
            const int ntf = fid >> 8;
            const int n = ntf * 16 + (lf & 15);
            const int k = half * 128 + ksf * 32 + (lf >> 4) * 8;
            *(u16x8_t*)(bs + fid * 8) = *(const u16x8_t*)(Wt + (long)n * 256 + k);
        }
        __syncthreads();
#pragma unroll
        for (int ks = 0; ks < 4; ++ks) {
            bf16x8_t af = __builtin_bit_cast(bf16x8_t, areg[half * 4 + ks]);
#pragma unroll
            for (int nt = 0; nt < 8; ++nt) {
                u16x8_t bv = *(const u16x8_t*)(bs + ((nt * 4 + ks) * 64 + lane) * 8);
                bf16x8_t bf = __builtin_bit_cast(bf16x8_t, bv);
                acc[nt] = __builtin_amdgcn_mfma_f32_16x16x32_bf16(af, bf, acc[nt], 0, 0, 0);
            }
        }
    }

    // epilogue: lane holds D[row = rbase + q*4 + r][col = nt*16 + m]
    float cs[8], cq[8];
    const int rw = rbase + q * 4;
#pragma unroll
    for (int nt = 0; nt < 8; ++nt) {
        cs[nt] = 0.f; cq[nt] = 0.f;
        const int c = nt * 16 + m;
        const float b = bl[c];
#pragma unroll
        for (int r = 0; r < 4; ++r) {
            const int grow = rw + r;
            if (grow < N_NODES) {
                float v = acc[nt][r] + b;
                v = (v >= 0.f) ? v : SLOPE * v;
                if (write_bf16) {
                    Pb[(long)grow * F + c] = f2b(v);
                } else {
                    Pf[(long)grow * F + c] = v;
                }
                cs[nt] += v;
                cq[nt] += v * v;
            }
        }
    }
#pragma unroll
    for (int nt = 0; nt < 8; ++nt) {
        cs[nt] += __shfl_xor(cs[nt], 16);
        cs[nt] += __shfl_xor(cs[nt], 32);
        cq[nt] += __shfl_xor(cq[nt], 16);
        cq[nt] += __shfl_xor(cq[nt], 32);
    }
    if (lane < 16) {
#pragma unroll
        for (int nt = 0; nt < 8; ++nt) {
            lsum[wave][nt * 16 + m] = cs[nt];
            lsq[wave][nt * 16 + m] = cq[nt];
        }
    }
    __syncthreads();
    if (tid < F) {
        float s = 0.f, s2 = 0.f;
#pragma unroll
        for (int w = 0; w < 4; ++w) {
            s += lsum[w][tid];
            s2 += lsq[w][tid];
        }
        atomicAdd(&sum[tid], s);
        atomicAdd(&sumsq[tid], s2);
    }
}

// computes scale/shift then re-zeroes sum/sumsq for the next layer (saves 2 memsets/layer)
__global__ void bn_prep(float* __restrict__ sum, float* __restrict__ sumsq,
                        const float* __restrict__ gamma, const float* __restrict__ beta,
                        float* __restrict__ scale, float* __restrict__ shift) {
    int j = threadIdx.x;
    if (j < F) {
        const float inv_n = 1.0f / (float)N_NODES;
        float mu = sum[j] * inv_n;
        float var = sumsq[j] * inv_n - mu * mu;
        float scl = gamma[j] * rsqrtf(var + BN_EPS);
        scale[j] = scl;
        shift[j] = beta[j] - mu * scl;
        sum[j] = 0.f;
        sumsq[j] = 0.f;
    }
}

// bf16 P -> bf16 h_next (layers 0-2): 8 features per thread
__global__ __launch_bounds__(256) void bn_apply_b(const unsigned short* __restrict__ Pb,
                                                  unsigned short* __restrict__ outb,
                                                  const float* __restrict__ scale,
                                                  const float* __restrict__ shift) {
    long i = (long)blockIdx.x * blockDim.x + threadIdx.x;  // uint4 index (8 bf16)
    if (i >= (long)N_NODES * (F / 8)) return;
    const int c8 = (int)(i & 15);  // feature block
    uint4 v = ((const uint4*)Pb)[i];
    const float4 sc0 = ((const float4*)scale)[c8 * 2];
    const float4 sc1 = ((const float4*)scale)[c8 * 2 + 1];
    const float4 sh0 = ((const float4*)shift)[c8 * 2];
    const float4 sh1 = ((const float4*)shift)[c8 * 2 + 1];
    uint4 o;
    o.x = (unsigned int)f2b(b2f_lo(v.x) * sc0.x + sh0.x) |
          ((unsigned int)f2b(b2f_hi(v.x) * sc0.y + sh0.y) << 16);
    o.y = (unsigned int)f2b(b2f_lo(v.y) * sc0.z + sh0.z) |
          ((unsigned int)f2b(b2f_hi(v.y) * sc0.w + sh0.w) << 16);
    o.z = (unsigned int)f2b(b2f_lo(v.z) * sc1.x + sh1.x) |
          ((unsigned int)f2b(b2f_hi(v.z) * sc1.y + sh1.y) << 16);
    o.w = (unsigned int)f2b(b2f_lo(v.w) * sc1.z + sh1.z) |
          ((unsigned int)f2b(b2f_hi(v.w) * sc1.w + sh1.w) << 16);
    ((uint4*)outb)[i] = o;
}

// fp32 P -> fp32 out, in place (final layer)
__global__ __launch_bounds__(256) void bn_apply_f(float* __restrict__ P,
                                                  const float* __restrict__ scale,
                                                  const float* __restrict__ shift) {
    long i = (long)blockIdx.x * blockDim.x + threadIdx.x;  // float4 index
    if (i >= (long)N_NODES * (F / 4)) return;
    const int c4 = (int)(i & 31);
    float4 v = ((float4*)P)[i];
    const float4 sc = ((const float4*)scale)[c4];
    const float4 sh = ((const float4*)shift)[c4];
    v.x = v.x * sc.x + sh.x;
    v.y = v.y * sc.y + sh.y;
    v.z = v.z * sc.z + sh.z;
    v.w = v.w * sc.w + sh.w;
    ((float4*)P)[i] = v;
}

// ---------------- launch ----------------

extern "C" void kernel_launch(void* const* d_in, const int* in_sizes, int n_in,
                              void* d_out, int out_size, void* d_ws, size_t ws_size,
                              hipStream_t stream) {
    const float* x     = (const float*)d_in[0];
    const int*   ei    = (const int*)d_in[1];
    const float* Wl    = (const float*)d_in[2];
    const float* bl    = (const float*)d_in[3];
    const float* Wr    = (const float*)d_in[4];
    const float* gamma = (const float*)d_in[5];
    const float* beta  = (const float*)d_in[6];
    float* out = (float*)d_out;

    const int* src = ei;
    const int* dst = ei + N_EDGES;

    char* w = (char*)d_ws;
    auto alloc = [&](size_t bytes) -> char* {
        char* p = w;
        w += (bytes + 255) & ~(size_t)255;
        return p;
    };
    unsigned short* hbA   = (unsigned short*)alloc((size_t)N_NODES * F * 2);
    unsigned short* hbB   = (unsigned short*)alloc((size_t)N_NODES * F * 2);
    unsigned short* aggb  = (unsigned short*)alloc((size_t)N_NODES * F * 2);
    unsigned short* Wt    = (unsigned short*)alloc((size_t)4 * F * 256 * 2);
    int*   deg      = (int*)alloc((size_t)N_NODES * 4);
    int*   row_start= (int*)alloc((size_t)N_NODES * 4);
    int*   cursor   = (int*)alloc((size_t)N_NODES * 4);
    int*   csr_src  = (int*)alloc((size_t)N_EDGES * 4);
    float* inv_deg  = (float*)alloc((size_t)N_NODES * 4);
    float* sum      = (float*)alloc(F * 4);   // adjacent to sumsq: one memset covers both
    float* sumsq    = (float*)alloc(F * 4);
    float* scale    = (float*)alloc(F * 4);
    float* shift    = (float*)alloc(F * 4);
    int*   counter  = (int*)alloc(256);

    hipMemsetAsync(deg, 0, (size_t)N_NODES * 4, stream);
    hipMemsetAsync(counter, 0, 4, stream);
    hipMemsetAsync(sum, 0, 2 * F * 4, stream);  // sum + sumsq (contiguous)

    hist_kernel<<<(N_EDGES + 255) / 256, 256, 0, stream>>>(dst, deg);
    alloc_kernel<<<(N_NODES + 255) / 256, 256, 0, stream>>>(deg, row_start, cursor, inv_deg,
                                                            counter);
    fill_kernel<<<(N_EDGES + 255) / 256, 256, 0, stream>>>(src, dst, cursor, csr_src);

    const int n4 = N_NODES * (F / 4);
    const int n8 = N_NODES * (F / 8);
    f2b_kernel<<<(n4 + 255) / 256, 256, 0, stream>>>(x, hbA);
    wprep_kernel<<<(4 * F * 256 + 255) / 256, 256, 0, stream>>>(Wl, Wr, Wt);

    unsigned short* Pb = (unsigned short*)out;  // reuse d_out as bf16 scratch (layers 0-2)

    unsigned short* hin = hbA;
    unsigned short* hnext = hbB;
    for (int i = 0; i < 4; ++i) {
        agg_kernel<<<(N_NODES + 3) / 4, 256, 0, stream>>>(hin, row_start, deg, csr_src, inv_deg,
                                                          aggb);

        const int last = (i == 3);
        gemm_mfma<<<(N_NODES + 63) / 64, 256, 0, stream>>>(
            aggb, hin, Wt + (size_t)i * F * 256, bl + (size_t)i * F,
            out, Pb, last ? 0 : 1, sum, sumsq);

        bn_prep<<<1, 128, 0, stream>>>(sum, sumsq, gamma + (size_t)i * F, beta + (size_t)i * F,
                                       scale, shift);
        if (last) {
            bn_apply_f<<<(n4 + 255) / 256, 256, 0, stream>>>(out, scale, shift);
        } else {
            bn_apply_b<<<(n8 + 255) / 256, 256, 0, stream>>>(Pb, hnext, scale, shift);
        }

        unsigned short* t = hin; hin = hnext; hnext = t;
    }
}